// Round 3
// baseline (826.236 us; speedup 1.0000x reference)
//
#include <hip/hip_runtime.h>
#include <stdint.h>

typedef float f32x4 __attribute__((ext_vector_type(4)));

// ---------------------------------------------------------------- helpers
__device__ __forceinline__ void gld16(const uint8_t* g, uint8_t* l) {
  // async global->LDS, 16B per lane; LDS dest must be linear (base + lane*16)
  __builtin_amdgcn_global_load_lds(
      (const __attribute__((address_space(1))) void*)g,
      (__attribute__((address_space(3))) void*)l, 16, 0, 0);
}

__device__ __forceinline__ float bf16_rne(float f) {
  uint32_t u = __float_as_uint(f);
  u = (u + 0x7fffu + ((u >> 16) & 1u)) & 0xffff0000u;
  return __uint_as_float(u);
}

__device__ __forceinline__ float quant_prep(float f, float s) {
  float b = bf16_rne(f);     // reference casts to bf16 first
  float v = b / s;           // IEEE fp32 divide, matches jnp
  return fminf(448.f, fmaxf(-448.f, v));
}

// ---------------------------------------------------------------- kernel 1: quantize x -> fp8
__global__ __launch_bounds__(256) void quant_x(
    const float* __restrict__ x, const float* __restrict__ isp,
    uint32_t* __restrict__ xq, int n4) {
  const float s = isp[0];
  int stride = gridDim.x * blockDim.x;
  for (int i = blockIdx.x * blockDim.x + threadIdx.x; i < n4; i += stride) {
    float4 v = ((const float4*)x)[i];
    float c0 = quant_prep(v.x, s);
    float c1 = quant_prep(v.y, s);
    float c2 = quant_prep(v.z, s);
    float c3 = quant_prep(v.w, s);
    int p = 0;
    p = __builtin_amdgcn_cvt_pk_fp8_f32(c0, c1, p, false); // bytes 0,1
    p = __builtin_amdgcn_cvt_pk_fp8_f32(c2, c3, p, true);  // bytes 2,3
    xq[i] = (uint32_t)p;
  }
}

// ---------------------------------------------------------------- kernel 2: weights int32[K,N] (values 0..255) -> uint8 [N,K]
__global__ __launch_bounds__(256) void transp_w(
    const int* __restrict__ qw, uint8_t* __restrict__ wt) {
  constexpr int K = 4096, N = 4096;
  __shared__ uint8_t t[64 * 80];   // 64x64 byte tile, stride 80 breaks pow2 banks
  const int n0 = blockIdx.x * 64, k0 = blockIdx.y * 64;
  const int tid = threadIdx.x;
  const int r = tid >> 2, c = tid & 3;
  // load 16 n-contiguous int32 of row (k0+r), truncate to bytes
  const int* src = qw + (size_t)(k0 + r) * N + n0 + c * 16;
  union { uint8_t b[16]; uint4 v; } o;
#pragma unroll
  for (int j = 0; j < 16; ++j) o.b[j] = (uint8_t)src[j];
  *(uint4*)(t + r * 80 + c * 16) = o.v;
  __syncthreads();
  // write: 16 k-contiguous bytes of wt row (n0+r)
#pragma unroll
  for (int j = 0; j < 16; ++j) o.b[j] = t[(c * 16 + j) * 80 + r];
  *(uint4*)(wt + (size_t)(n0 + r) * K + k0 + c * 16) = o.v;
}

// ---------------------------------------------------------------- kernel 3: fp8 GEMM, m97 structure
// A = xq [M,K] fp8, B^T = wt [N,K] fp8, out[M,N] f32 = (A.B)*is*ws[n] + bias[n]
__global__ __launch_bounds__(256) void gemm_fp8(
    const uint8_t* __restrict__ xq, const uint8_t* __restrict__ wt,
    const float* __restrict__ wscale, const float* __restrict__ isp,
    const float* __restrict__ bias, float* __restrict__ out, int M) {
  constexpr int K = 4096, N = 4096;
  __shared__ uint8_t As[128 * 64];
  __shared__ uint8_t Bs[128 * 64];

  const int tid = threadIdx.x;
  const int l = tid & 63;          // lane
  const int w = tid >> 6;          // wave 0..3
  const int wm = w >> 1, wn = w & 1;
  const int m0 = blockIdx.y * 128, n0 = blockIdx.x * 128;

  f32x4 acc[4][4] = {};

  // staging geometry: per wave 1KB linear chunk; lane l covers row w*16+(l>>2), bytes (l&3)*16
  const int srow = w * 16 + (l >> 2);
  const int scol = (l & 3) * 16;
  const uint8_t* agp = xq + (size_t)(m0 + srow) * K + scol;
  const uint8_t* bgp = wt + (size_t)(n0 + srow) * K + scol;
  uint8_t* al = As + w * 1024 + l * 16;
  uint8_t* bl = Bs + w * 1024 + l * 16;

  const int fr = l & 15;           // fragment row (A) / col (B)
  const int fk = (l >> 4) * 8;     // fragment k-offset (bytes)

  for (int kt = 0; kt < K; kt += 64) {
    gld16(agp + kt, al);
    gld16(agp + kt + (size_t)64 * K, al + 4096);
    gld16(bgp + kt, bl);
    gld16(bgp + kt + (size_t)64 * K, bl + 4096);
    __syncthreads();   // compiler drains vmcnt before barrier

#pragma unroll
    for (int kk = 0; kk < 64; kk += 32) {
      long a[4], b[4];
#pragma unroll
      for (int mi = 0; mi < 4; ++mi)
        a[mi] = *(const long*)(As + (wm * 64 + mi * 16 + fr) * 64 + kk + fk);
#pragma unroll
      for (int ni = 0; ni < 4; ++ni)
        b[ni] = *(const long*)(Bs + (wn * 64 + ni * 16 + fr) * 64 + kk + fk);
#pragma unroll
      for (int mi = 0; mi < 4; ++mi)
#pragma unroll
        for (int ni = 0; ni < 4; ++ni)
          acc[mi][ni] = __builtin_amdgcn_mfma_f32_16x16x32_fp8_fp8(
              a[mi], b[ni], acc[mi][ni], 0, 0, 0);
    }
    __syncthreads();
  }

  // epilogue: C/D layout col = l&15, row = (l>>4)*4 + r  (dtype-independent, m89/m121)
  const float is = isp[0];
#pragma unroll
  for (int ni = 0; ni < 4; ++ni) {
    const int col = n0 + wn * 64 + ni * 16 + fr;
    const float sc = is * wscale[col];
    const float bb = bias[col];
#pragma unroll
    for (int mi = 0; mi < 4; ++mi) {
      const int row = m0 + wm * 64 + mi * 16 + (l >> 4) * 4;
      float* op = out + (size_t)row * N + col;
#pragma unroll
      for (int r = 0; r < 4; ++r)
        op[(size_t)r * N] = acc[mi][ni][r] * sc + bb;
    }
  }
}

// ---------------------------------------------------------------- launch
extern "C" void kernel_launch(void* const* d_in, const int* in_sizes, int n_in,
                              void* d_out, int out_size, void* d_ws, size_t ws_size,
                              hipStream_t stream) {
  const float* x      = (const float*)d_in[0];
  const int*   qw     = (const int*)d_in[1];     // uint8 values materialized as int32
  const float* wscale = (const float*)d_in[2];
  const float* isp    = (const float*)d_in[3];
  const float* bias   = (const float*)d_in[4];
  float*       out    = (float*)d_out;

  constexpr int K = 4096, N = 4096;
  const int M = in_sizes[0] / K;      // 8192

  uint8_t* xq = (uint8_t*)d_ws;                 // M*K bytes
  uint8_t* wt = xq + (size_t)M * K;             // N*K bytes

  quant_x<<<2048, 256, 0, stream>>>(x, isp, (uint32_t*)xq, M * K / 4);
  transp_w<<<dim3(N / 64, K / 64), 256, 0, stream>>>(qw, wt);
  gemm_fp8<<<dim3(N / 128, M / 128), 256, 0, stream>>>(xq, wt, wscale, isp, bias, out, M);
}

// Round 4
// 446.246 us; speedup vs baseline: 1.8515x; 1.8515x over previous
//
#include <hip/hip_runtime.h>
#include <stdint.h>

typedef float f32x4 __attribute__((ext_vector_type(4)));
typedef int   i32x4 __attribute__((ext_vector_type(4)));
typedef int   i32x8 __attribute__((ext_vector_type(8)));

// ---------------------------------------------------------------- helpers
__device__ __forceinline__ void gld16(const uint8_t* g, uint8_t* l) {
  // async global->LDS, 16B per lane; LDS dest linear (wave base + lane*16)
  __builtin_amdgcn_global_load_lds(
      (const __attribute__((address_space(1))) void*)g,
      (__attribute__((address_space(3))) void*)l, 16, 0, 0);
}

__device__ __forceinline__ float bf16_rne(float f) {
  uint32_t u = __float_as_uint(f);
  u = (u + 0x7fffu + ((u >> 16) & 1u)) & 0xffff0000u;
  return __uint_as_float(u);
}

__device__ __forceinline__ float quant_prep(float f, float s) {
  float b = bf16_rne(f);     // reference casts to bf16 first
  float v = b / s;           // IEEE fp32 divide, matches jnp
  return fminf(448.f, fmaxf(-448.f, v));
}

// ---------------------------------------------------------------- kernel 1: quantize x -> fp8
__global__ __launch_bounds__(256) void quant_x(
    const float* __restrict__ x, const float* __restrict__ isp,
    uint32_t* __restrict__ xq, int n4) {
  const float s = isp[0];
  int stride = gridDim.x * blockDim.x;
  for (int i = blockIdx.x * blockDim.x + threadIdx.x; i < n4; i += stride) {
    float4 v = ((const float4*)x)[i];
    float c0 = quant_prep(v.x, s);
    float c1 = quant_prep(v.y, s);
    float c2 = quant_prep(v.z, s);
    float c3 = quant_prep(v.w, s);
    int p = 0;
    p = __builtin_amdgcn_cvt_pk_fp8_f32(c0, c1, p, false); // bytes 0,1
    p = __builtin_amdgcn_cvt_pk_fp8_f32(c2, c3, p, true);  // bytes 2,3
    xq[i] = (uint32_t)p;
  }
}

// ---------------------------------------------------------------- kernel 2: weights int32[K,N] (values 0..255) -> uint8 [N,K]
__global__ __launch_bounds__(256) void transp_w(
    const int* __restrict__ qw, uint8_t* __restrict__ wt) {
  constexpr int K = 4096, N = 4096;
  __shared__ uint8_t t[64 * 80];   // 64x64 byte tile, stride 80 breaks pow2 banks
  const int n0 = blockIdx.x * 64, k0 = blockIdx.y * 64;
  const int tid = threadIdx.x;
  const int r = tid >> 2, c = tid & 3;
  // load 16 n-contiguous int32 of row (k0+r), truncate to bytes
  const int* src = qw + (size_t)(k0 + r) * N + n0 + c * 16;
  union { uint8_t b[16]; uint4 v; } o;
#pragma unroll
  for (int j = 0; j < 16; ++j) o.b[j] = (uint8_t)src[j];
  *(uint4*)(t + r * 80 + c * 16) = o.v;
  __syncthreads();
  // write: 16 k-contiguous bytes of wt row (n0+r)
#pragma unroll
  for (int j = 0; j < 16; ++j) o.b[j] = t[(c * 16 + j) * 80 + r];
  *(uint4*)(wt + (size_t)(n0 + r) * K + k0 + c * 16) = o.v;
}

// ---------------------------------------------------------------- kernel 3: MX-fp8 GEMM (unit scales == exact fp8 GEMM at 2x rate)
// A = xq [M,K] fp8, B^T = wt [N,K] fp8, out[M,N] f32 = (A.B)*is*ws[n] + bias[n]
// 128x128 tile, BK=128 bytes, 16B-granular XOR swizzle (chunk ^= row&7) applied
// on BOTH sides: pre-swizzled global source (LDS dest linear, rule #21) and
// swizzled ds_read addresses.
__device__ __forceinline__ i32x8 ld_frag(const uint8_t* base, int row, int g) {
  const int s = row & 7;
  const i32x4 lo = *(const i32x4*)(base + row * 128 + (((2 * g)     ^ s) * 16));
  const i32x4 hi = *(const i32x4*)(base + row * 128 + (((2 * g + 1) ^ s) * 16));
  i32x8 r;
  r[0] = lo[0]; r[1] = lo[1]; r[2] = lo[2]; r[3] = lo[3];
  r[4] = hi[0]; r[5] = hi[1]; r[6] = hi[2]; r[7] = hi[3];
  return r;
}

__global__ __launch_bounds__(256) void gemm_mxfp8(
    const uint8_t* __restrict__ xq, const uint8_t* __restrict__ wt,
    const float* __restrict__ wscale, const float* __restrict__ isp,
    const float* __restrict__ bias, float* __restrict__ out, int M) {
  constexpr int K = 4096, N = 4096, BK = 128;
  __shared__ uint8_t As[128 * BK];   // 16 KB
  __shared__ uint8_t Bs[128 * BK];   // 16 KB

  const int tid = threadIdx.x;
  const int l = tid & 63;          // lane
  const int w = tid >> 6;          // wave 0..3
  const int wm = w >> 1, wn = w & 1;

  // bijective XCD swizzle (grid = 2048 = 8*256)
  const int nwg = gridDim.x;
  const int cpx = nwg >> 3;
  const int bid = blockIdx.x;
  const int swz = (bid & 7) * cpx + (bid >> 3);
  const int m0 = (swz >> 5) * 128;   // 64 M-tiles
  const int n0 = (swz & 31) * 128;   // 32 N-tiles

  f32x4 acc[4][4] = {};

  const int fr = l & 15;           // fragment row (A) / col (B)
  const int g  = l >> 4;           // k-group: bytes 32g..32g+31 of the row

  // staging geometry: unit u = c*256 + tid (16B units); row = u>>3, chunk = u&7
  // LDS dest linear at u*16; global source chunk pre-swizzled: (u&7) ^ (row&7)
  int srow[4], scol[4];
#pragma unroll
  for (int c = 0; c < 4; ++c) {
    int u = c * 256 + tid;
    srow[c] = u >> 3;
    scol[c] = ((u & 7) ^ (srow[c] & 7)) * 16;
  }

  for (int kt = 0; kt < K; kt += BK) {
#pragma unroll
    for (int c = 0; c < 4; ++c) {
      gld16(xq + (size_t)(m0 + srow[c]) * K + kt + scol[c], As + (c * 256 + tid) * 16);
      gld16(wt + (size_t)(n0 + srow[c]) * K + kt + scol[c], Bs + (c * 256 + tid) * 16);
    }
    __syncthreads();   // compiler drains vmcnt before barrier

    i32x8 a[4], b[4];
#pragma unroll
    for (int mi = 0; mi < 4; ++mi)
      a[mi] = ld_frag(As, wm * 64 + mi * 16 + fr, g);
#pragma unroll
    for (int ni = 0; ni < 4; ++ni)
      b[ni] = ld_frag(Bs, wn * 64 + ni * 16 + fr, g);

#pragma unroll
    for (int mi = 0; mi < 4; ++mi)
#pragma unroll
      for (int ni = 0; ni < 4; ++ni)
        acc[mi][ni] = __builtin_amdgcn_mfma_scale_f32_16x16x128_f8f6f4(
            a[mi], b[ni], acc[mi][ni],
            0 /*cbsz: fp8*/, 0 /*blgp: fp8*/,
            0, 0x7F7F7F7Fu /*scale A = 2^0*/,
            0, 0x7F7F7F7Fu /*scale B = 2^0*/);
    __syncthreads();
  }

  // epilogue: C/D layout col = l&15, row = (l>>4)*4 + r (shape-determined)
  const float is = isp[0];
#pragma unroll
  for (int ni = 0; ni < 4; ++ni) {
    const int col = n0 + wn * 64 + ni * 16 + fr;
    const float sc = is * wscale[col];
    const float bb = bias[col];
#pragma unroll
    for (int mi = 0; mi < 4; ++mi) {
      const int row = m0 + wm * 64 + mi * 16 + g * 4;
      float* op = out + (size_t)row * N + col;
#pragma unroll
      for (int r = 0; r < 4; ++r)
        op[(size_t)r * N] = acc[mi][ni][r] * sc + bb;
    }
  }
}

// ---------------------------------------------------------------- launch
extern "C" void kernel_launch(void* const* d_in, const int* in_sizes, int n_in,
                              void* d_out, int out_size, void* d_ws, size_t ws_size,
                              hipStream_t stream) {
  const float* x      = (const float*)d_in[0];
  const int*   qw     = (const int*)d_in[1];     // uint8 values materialized as int32
  const float* wscale = (const float*)d_in[2];
  const float* isp    = (const float*)d_in[3];
  const float* bias   = (const float*)d_in[4];
  float*       out    = (float*)d_out;

  constexpr int K = 4096, N = 4096;
  const int M = in_sizes[0] / K;      // 8192

  uint8_t* xq = (uint8_t*)d_ws;                 // M*K bytes
  uint8_t* wt = xq + (size_t)M * K;             // N*K bytes

  quant_x<<<2048, 256, 0, stream>>>(x, isp, (uint32_t*)xq, M * K / 4);
  transp_w<<<dim3(N / 64, K / 64), 256, 0, stream>>>(qw, wt);
  gemm_mxfp8<<<(M / 128) * (N / 128), 256, 0, stream>>>(xq, wt, wscale, isp, bias, out, M);
}

// Round 6
// 440.329 us; speedup vs baseline: 1.8764x; 1.0134x over previous
//
#include <hip/hip_runtime.h>
#include <stdint.h>

typedef float f32x4 __attribute__((ext_vector_type(4)));
typedef int   i32x4 __attribute__((ext_vector_type(4)));
typedef int   i32x8 __attribute__((ext_vector_type(8)));

// ---------------------------------------------------------------- helpers
__device__ __forceinline__ void gld16(const uint8_t* g, uint8_t* l) {
  // async global->LDS, 16B per lane; LDS dest linear (wave base + lane*16)
  __builtin_amdgcn_global_load_lds(
      (const __attribute__((address_space(1))) void*)g,
      (__attribute__((address_space(3))) void*)l, 16, 0, 0);
}

__device__ __forceinline__ float bf16_rne(float f) {
  uint32_t u = __float_as_uint(f);
  u = (u + 0x7fffu + ((u >> 16) & 1u)) & 0xffff0000u;
  return __uint_as_float(u);
}

__device__ __forceinline__ float quant_prep(float f, float s) {
  float b = bf16_rne(f);     // reference casts to bf16 first
  float v = b / s;           // IEEE fp32 divide, matches jnp
  return fminf(448.f, fmaxf(-448.f, v));
}

// ---------------------------------------------------------------- kernel 1: quantize x -> fp8
__global__ __launch_bounds__(256) void quant_x(
    const float* __restrict__ x, const float* __restrict__ isp,
    uint32_t* __restrict__ xq, int n4) {
  const float s = isp[0];
  int stride = gridDim.x * blockDim.x;
  for (int i = blockIdx.x * blockDim.x + threadIdx.x; i < n4; i += stride) {
    float4 v = ((const float4*)x)[i];
    float c0 = quant_prep(v.x, s);
    float c1 = quant_prep(v.y, s);
    float c2 = quant_prep(v.z, s);
    float c3 = quant_prep(v.w, s);
    int p = 0;
    p = __builtin_amdgcn_cvt_pk_fp8_f32(c0, c1, p, false); // bytes 0,1
    p = __builtin_amdgcn_cvt_pk_fp8_f32(c2, c3, p, true);  // bytes 2,3
    xq[i] = (uint32_t)p;
  }
}

// ---------------------------------------------------------------- kernel 2: weights int32[K,N] (values 0..255) -> uint8 [N,K]
// coalesced: 4x dwordx4 loads/thread (lane-contiguous), LDS stride 68 (2-way only)
__global__ __launch_bounds__(256) void transp_w(
    const int* __restrict__ qw, uint8_t* __restrict__ wt) {
  constexpr int K = 4096, N = 4096;
  __shared__ uint8_t t[64 * 68];
  const int n0 = blockIdx.x * 64, k0 = blockIdx.y * 64;
  const int tid = threadIdx.x;
  const int lr = tid >> 4;       // 0..15
  const int lc = tid & 15;       // int32 col group (4 int32 = 4 out bytes)
#pragma unroll
  for (int p = 0; p < 4; ++p) {
    const int row = p * 16 + lr;
    int4 v = *(const int4*)(qw + (size_t)(k0 + row) * N + n0 + lc * 4);
    uchar4 b = make_uchar4((uint8_t)v.x, (uint8_t)v.y, (uint8_t)v.z, (uint8_t)v.w);
    *(uchar4*)(t + row * 68 + lc * 4) = b;
  }
  __syncthreads();
  // write: 16 k-contiguous bytes of wt row (n0+r)
  const int r = tid >> 2, c = tid & 3;
  union { uint8_t b[16]; uint4 v; } o;
#pragma unroll
  for (int j = 0; j < 16; ++j) o.b[j] = t[(c * 16 + j) * 68 + r];
  *(uint4*)(wt + (size_t)(n0 + r) * K + k0 + c * 16) = o.v;
}

// ---------------------------------------------------------------- kernel 3: MX-fp8 GEMM (unit scales), 128x128 tile, BK=128,
// double-buffered 2-phase: prefetch next tile BEFORE compute; statically
// distinct LDS buffers so the compiler cannot alias them (no early vmcnt).
__device__ __forceinline__ i32x8 ld_frag(const uint8_t* base, int row, int g) {
  const int s = row & 7;
  const i32x4 lo = *(const i32x4*)(base + row * 128 + (((2 * g)     ^ s) * 16));
  const i32x4 hi = *(const i32x4*)(base + row * 128 + (((2 * g + 1) ^ s) * 16));
  i32x8 r;
  r[0] = lo[0]; r[1] = lo[1]; r[2] = lo[2]; r[3] = lo[3];
  r[4] = hi[0]; r[5] = hi[1]; r[6] = hi[2]; r[7] = hi[3];
  return r;
}

__global__ __launch_bounds__(256) void gemm_mxfp8(
    const uint8_t* __restrict__ xq, const uint8_t* __restrict__ wt,
    const float* __restrict__ wscale, const float* __restrict__ isp,
    const float* __restrict__ bias, float* __restrict__ out, int M) {
  constexpr int K = 4096, N = 4096, BK = 128;
  __shared__ uint8_t As0[128 * BK];
  __shared__ uint8_t Bs0[128 * BK];
  __shared__ uint8_t As1[128 * BK];
  __shared__ uint8_t Bs1[128 * BK];   // 4 x 16KB = 64KB -> 2 blocks/CU

  const int tid = threadIdx.x;
  const int l = tid & 63;          // lane
  const int w = tid >> 6;          // wave 0..3
  const int wm = w >> 1, wn = w & 1;

  // bijective XCD swizzle (grid = 2048 = 8*256)
  const int cpx = gridDim.x >> 3;
  const int bid = blockIdx.x;
  const int swz = (bid & 7) * cpx + (bid >> 3);
  const int m0 = (swz >> 5) * 128;   // 64 M-tiles
  const int n0 = (swz & 31) * 128;   // 32 N-tiles

  f32x4 acc[4][4] = {};

  const int fr = l & 15;           // fragment row (A) / col (B)
  const int g  = l >> 4;           // k-group: bytes 32g..32g+31

  // staging geometry: unit u = c*256 + tid; row = u>>3, chunk = u&7
  // LDS dest linear at u*16; global source chunk pre-swizzled (rule #21)
  int srow[4], scol[4];
#pragma unroll
  for (int c = 0; c < 4; ++c) {
    int u = c * 256 + tid;
    srow[c] = u >> 3;
    scol[c] = ((u & 7) ^ (srow[c] & 7)) * 16;
  }
  const uint8_t* abase = xq + (size_t)m0 * K;
  const uint8_t* bbase = wt + (size_t)n0 * K;

#define STAGE(AD, BD, KT)                                                      \
  _Pragma("unroll")                                                            \
  for (int c = 0; c < 4; ++c) {                                                \
    gld16(abase + (size_t)srow[c] * K + (KT) + scol[c], (AD) + (c * 256 + tid) * 16); \
    gld16(bbase + (size_t)srow[c] * K + (KT) + scol[c], (BD) + (c * 256 + tid) * 16); \
  }

#define COMPUTE(AS, BS)                                                        \
  {                                                                            \
    i32x8 a[4], b[4];                                                          \
    _Pragma("unroll")                                                          \
    for (int mi = 0; mi < 4; ++mi) a[mi] = ld_frag((AS), wm * 64 + mi * 16 + fr, g); \
    _Pragma("unroll")                                                          \
    for (int ni = 0; ni < 4; ++ni) b[ni] = ld_frag((BS), wn * 64 + ni * 16 + fr, g); \
    _Pragma("unroll")                                                          \
    for (int mi = 0; mi < 4; ++mi)                                             \
      _Pragma("unroll")                                                        \
      for (int ni = 0; ni < 4; ++ni)                                           \
        acc[mi][ni] = __builtin_amdgcn_mfma_scale_f32_16x16x128_f8f6f4(        \
            a[mi], b[ni], acc[mi][ni], 0, 0, 0, 0x7F7F7F7Fu, 0, 0x7F7F7F7Fu);  \
  }

  STAGE(As0, Bs0, 0);
  __syncthreads();
  for (int kt = 0; kt < K; kt += 2 * BK) {
    if (kt + BK < K) { STAGE(As1, Bs1, kt + BK); }
    COMPUTE(As0, Bs0);
    __syncthreads();                  // drains prefetch vmcnt AFTER compute
    if (kt + 2 * BK < K) { STAGE(As0, Bs0, kt + 2 * BK); }
    COMPUTE(As1, Bs1);
    __syncthreads();
  }
#undef STAGE
#undef COMPUTE

  // epilogue: C/D layout col = l&15, row = (l>>4)*4 + r (shape-determined)
  const float is = isp[0];
#pragma unroll
  for (int ni = 0; ni < 4; ++ni) {
    const int col = n0 + wn * 64 + ni * 16 + fr;
    const float sc = is * wscale[col];
    const float bb = bias[col];
#pragma unroll
    for (int mi = 0; mi < 4; ++mi) {
      const int row = m0 + wm * 64 + mi * 16 + g * 4;
      float* op = out + (size_t)row * N + col;
#pragma unroll
      for (int r = 0; r < 4; ++r)
        op[(size_t)r * N] = acc[mi][ni][r] * sc + bb;
    }
  }
}

// ---------------------------------------------------------------- launch
extern "C" void kernel_launch(void* const* d_in, const int* in_sizes, int n_in,
                              void* d_out, int out_size, void* d_ws, size_t ws_size,
                              hipStream_t stream) {
  const float* x      = (const float*)d_in[0];
  const int*   qw     = (const int*)d_in[1];     // uint8 values materialized as int32
  const float* wscale = (const float*)d_in[2];
  const float* isp    = (const float*)d_in[3];
  const float* bias   = (const float*)d_in[4];
  float*       out    = (float*)d_out;

  constexpr int K = 4096, N = 4096;
  const int M = in_sizes[0] / K;      // 8192

  uint8_t* xq = (uint8_t*)d_ws;                 // M*K bytes
  uint8_t* wt = xq + (size_t)M * K;             // N*K bytes

  quant_x<<<2048, 256, 0, stream>>>(x, isp, (uint32_t*)xq, M * K / 4);
  transp_w<<<dim3(N / 64, K / 64), 256, 0, stream>>>(qw, wt);
  gemm_mxfp8<<<(M / 128) * (N / 128), 256, 0, stream>>>(xq, wt, wscale, isp, bias, out, M);
}